// Round 6
// baseline (500.948 us; speedup 1.0000x reference)
//
#include <hip/hip_runtime.h>
#include <hip/hip_fp16.h>
#include <stdint.h>

#define IN_F   4096
#define OUT_F  4096
#define M_ROWS 8192

typedef _Float16 v8h __attribute__((ext_vector_type(8)));
typedef float    v4f __attribute__((ext_vector_type(4)));

// ---------------- Kernel 1: dequant 3-bit groups -> f16 weight ----------------
__global__ void dequant_kernel(const int* __restrict__ q,
                               const float* __restrict__ norm,
                               _Float16* __restrict__ w) {
    int g = blockIdx.x * blockDim.x + threadIdx.x;   // 524288 groups
    const int4* p = (const int4*)(q + (size_t)g * 12);
    int4 q0 = p[0], q1 = p[1], q2 = p[2];
    uint32_t b[12] = {(uint32_t)q0.x, (uint32_t)q0.y, (uint32_t)q0.z, (uint32_t)q0.w,
                      (uint32_t)q1.x, (uint32_t)q1.y, (uint32_t)q1.z, (uint32_t)q1.w,
                      (uint32_t)q2.x, (uint32_t)q2.y, (uint32_t)q2.z, (uint32_t)q2.w};
    uint64_t lo = 0, hi = 0;
#pragma unroll
    for (int i = 0; i < 8; ++i) lo |= (uint64_t)(b[i] & 0xff) << (8 * i);
#pragma unroll
    for (int i = 0; i < 8; ++i) hi |= (uint64_t)(b[4 + i] & 0xff) << (8 * i);
    float nrm = norm[g];
    float scale = nrm * (2.0f / 7.0f);
    v8h out[4];
#pragma unroll
    for (int i = 0; i < 32; ++i) {
        int p3 = 3 * i;
        uint32_t qv = (i <= 20) ? (uint32_t)((lo >> p3) & 7)
                                : (uint32_t)((hi >> (p3 - 32)) & 7);
        float v = fmaf((float)qv, scale, -nrm);
        out[i >> 3][i & 7] = (_Float16)v;
    }
    v8h* dst = (v8h*)(w + (size_t)g * 32);
    dst[0] = out[0]; dst[1] = out[1]; dst[2] = out[2]; dst[3] = out[3];
}

// ---------------- Kernel 2: cast x f32 -> f16 ----------------
__global__ void castx_kernel(const float* __restrict__ x, _Float16* __restrict__ o) {
    size_t i = ((size_t)blockIdx.x * blockDim.x + threadIdx.x) * 8;
    float4 a = *(const float4*)(x + i);
    float4 b = *(const float4*)(x + i + 4);
    v8h r;
    r[0] = (_Float16)a.x; r[1] = (_Float16)a.y; r[2] = (_Float16)a.z; r[3] = (_Float16)a.w;
    r[4] = (_Float16)b.x; r[5] = (_Float16)b.y; r[6] = (_Float16)b.z; r[7] = (_Float16)b.w;
    *(v8h*)(o + i) = r;
}

// ====== Kernel 3: 256x256 GEMM, m201-style 2-barrier sandwich phases ======
// R5 post-mortem: 3 different source-level schedules all compiled to the same
// ~2340 cyc/step (compiler reorders freely inside a single-barrier body; asm
// clobbers don't pin DS ops -- BARRIERS do). This version enforces the proven
// m201 phase structure (1563-1728 TF on this chip, same geometry):
//   per phase: {ds_reads || 2 gload_lds -> barrier -> lgkmcnt(0)+sched_barrier
//               -> setprio(1) -> 16 MFMA -> setprio(0) -> [vmcnt(N)] -> barrier}
// 2 phases per K-32 slot (acc rows 0-3 then 4-7); a wave finishes ISSUING its
// 16 MFMAs in ~200 cyc, passes barrier 2, and issues next phase's ds_reads while
// the MFMA pipe drains -- the overlap single-barrier bodies never achieved.
// vmcnt(8) once per slot (never 0): 3 slots in flight, retires slot u+1.
// Race-freedom: reads of slot S complete before phase's 2nd barrier (lgkmcnt(0)
// precedes MFMA); the stage overwriting S issues only after that barrier.
// 4-slot FIFO, XOR swizzle (0 conflicts measured), linear gload_lds dest +
// inverse-swizzled global source unchanged.
#define KU 32

__global__ void __launch_bounds__(512, 2)
gemm_kernel(const _Float16* __restrict__ A,   // [M_ROWS][IN_F]
            const _Float16* __restrict__ B,   // [OUT_F][IN_F]
            const float* __restrict__ bias,
            float* __restrict__ C) {
    __shared__ __align__(16) char smem[131072];   // 4 x 32 KB slots

    int pid = blockIdx.x;                 // 512 = 32 pm x 16 pn
    int c  = pid & 7;                     // XCD (round-robin dispatch)
    int s  = pid >> 3;                    // 0..63 within XCD
    int pm = ((c & 3) << 3) | (s & 7);    // 8x8 rectangle per XCD (FETCH 197 MB)
    int pn = ((c >> 2) << 3) | (s >> 3);
    const int m0 = pm * 256, n0 = pn * 256;

    int t = threadIdx.x;
    int lane = t & 63, wid = t >> 6;
    int wm = wid >> 2, wn = wid & 3;
    int lr = lane & 15, qd = lane >> 4;

    // read-side swizzle: chunk is a per-lane constant (0 conflicts measured)
    int chr  = (((lane & 1) << 2) | qd) ^ ((lr >> 1) & 7);
    int aoff = wm * 8192 + (lr >> 1) * 128 + chr * 16;
    int boff = 16384 + wn * 4096 + (lr >> 1) * 128 + chr * 16;

    // stage-side: linear LDS dest, inverse-swizzled global source
    int line = t >> 3, chl = t & 7;
    int chd  = chl ^ (line & 7);
    int rr0  = 2 * line + (chd >> 2);
    int cc0  = chd & 3;
    const _Float16* gA0 = A + (size_t)(m0 + rr0) * IN_F + cc0 * 8;
    const _Float16* gA1 = gA0 + (size_t)128 * IN_F;
    const _Float16* gB0 = B + (size_t)(n0 + rr0) * IN_F + cc0 * 8;
    const _Float16* gB1 = gB0 + (size_t)128 * IN_F;
    const int dA = t * 16;
    const int dB = 16384 + t * 16;

    v4f acc[8][4] = {};
    v8h pa[4], bb[4];   // pa reused across the 2 phases; bb lives through the slot

#define RD(SLOT, OFF) (*(const v8h*)(smem + (SLOT) * 32768 + (OFF)))

#define GLL(SRC, DOFF)                                                              \
    __builtin_amdgcn_global_load_lds(                                               \
        (const __attribute__((address_space(1))) void*)(SRC),                       \
        (__attribute__((address_space(3))) void*)(smem + (DOFF)), 16, 0, 0)

// Phase A of slot SL: read a0-3 + b0-3, stage A-half of slot SL+3, MFMA rows 0-3.
#define PHASE_A(SL, DO_STAGE)                                                       \
    do {                                                                            \
        _Pragma("unroll") for (int i = 0; i < 4; ++i)                               \
            pa[i] = RD(SL, aoff + i * 1024);                                        \
        _Pragma("unroll") for (int j = 0; j < 4; ++j)                               \
            bb[j] = RD(SL, boff + j * 1024);                                        \
        if (DO_STAGE) {                                                             \
            GLL(gA0, (((SL) + 3) & 3) * 32768 + dA);                                \
            GLL(gA1, (((SL) + 3) & 3) * 32768 + dA + 8192);                         \
        }                                                                           \
        __builtin_amdgcn_s_barrier();                                               \
        asm volatile("s_waitcnt lgkmcnt(0)" ::: "memory");                          \
        __builtin_amdgcn_sched_barrier(0);                                          \
        __builtin_amdgcn_s_setprio(1);                                              \
        _Pragma("unroll") for (int i = 0; i < 4; ++i)                               \
            _Pragma("unroll") for (int j = 0; j < 4; ++j)                           \
                acc[i][j] = __builtin_amdgcn_mfma_f32_16x16x32_f16(                 \
                    pa[i], bb[j], acc[i][j], 0, 0, 0);                              \
        __builtin_amdgcn_s_setprio(0);                                              \
        __builtin_amdgcn_s_barrier();                                               \
    } while (0)

// Phase B of slot SL: read a4-7, stage B-half of slot SL+3, MFMA rows 4-7,
// counted vmcnt before the closing barrier (once per slot, never 0 mid-loop).
#define PHASE_B(SL, DO_STAGE, VM)                                                   \
    do {                                                                            \
        _Pragma("unroll") for (int i = 0; i < 4; ++i)                               \
            pa[i] = RD(SL, aoff + (i + 4) * 1024);                                  \
        if (DO_STAGE) {                                                             \
            GLL(gB0, (((SL) + 3) & 3) * 32768 + dB);                                \
            GLL(gB1, (((SL) + 3) & 3) * 32768 + dB + 8192);                         \
            gA0 += KU; gA1 += KU; gB0 += KU; gB1 += KU;                             \
        }                                                                           \
        __builtin_amdgcn_s_barrier();                                               \
        asm volatile("s_waitcnt lgkmcnt(0)" ::: "memory");                          \
        __builtin_amdgcn_sched_barrier(0);                                          \
        __builtin_amdgcn_s_setprio(1);                                              \
        _Pragma("unroll") for (int i = 0; i < 4; ++i)                               \
            _Pragma("unroll") for (int j = 0; j < 4; ++j)                           \
                acc[i + 4][j] = __builtin_amdgcn_mfma_f32_16x16x32_f16(             \
                    pa[i], bb[j], acc[i + 4][j], 0, 0, 0);                          \
        __builtin_amdgcn_s_setprio(0);                                              \
        asm volatile("s_waitcnt vmcnt(" #VM ")" ::: "memory");                      \
        __builtin_amdgcn_s_barrier();                                               \
    } while (0)

#define BODY(SL, DO_STAGE, VM)  do { PHASE_A(SL, DO_STAGE); PHASE_B(SL, DO_STAGE, VM); } while (0)

#define STAGE_SLOT(SL2)                                                             \
    do {                                                                            \
        GLL(gA0, (SL2) * 32768 + dA);                                               \
        GLL(gA1, (SL2) * 32768 + dA + 8192);                                        \
        GLL(gB0, (SL2) * 32768 + dB);                                               \
        GLL(gB1, (SL2) * 32768 + dB + 8192);                                        \
        gA0 += KU; gA1 += KU; gB0 += KU; gB1 += KU;                                 \
    } while (0)

    // prologue: stage slots 0,1,2 (12 loads); vmcnt(8) -> slot 0 resident.
    STAGE_SLOT(0);
    STAGE_SLOT(1);
    STAGE_SLOT(2);
    asm volatile("s_waitcnt vmcnt(8)" ::: "memory");
    __builtin_amdgcn_s_barrier();

    // bodies 0..123: stage slot u+3 (2 loads in phase A, 2 in phase B).
    // End-of-body vmcnt(8): 12 outstanding (slots u+1,u+2,u+3) -> retire u+1.
#pragma unroll 1
    for (int b4 = 0; b4 < 31; ++b4) {
        BODY(0, 1, 8);
        BODY(1, 1, 8);
        BODY(2, 1, 8);
        BODY(3, 1, 8);
    }
    // body 124 stages slot 127 (last); 125..127 drain: vmcnt 8 -> 4 -> 0 -> 0.
    BODY(0, 1, 8);
    BODY(1, 0, 4);
    BODY(2, 0, 0);
    BODY(3, 0, 0);
#undef BODY
#undef PHASE_A
#undef PHASE_B
#undef STAGE_SLOT
#undef GLL
#undef RD

    // epilogue: C/D layout col = lane&15, row = qd*4 + rr
#pragma unroll
    for (int j = 0; j < 4; ++j) {
        int n = n0 + wn * 64 + j * 16 + lr;
        float bf = bias[n];
#pragma unroll
        for (int i = 0; i < 8; ++i) {
            int m = m0 + wm * 128 + i * 16 + qd * 4;
#pragma unroll
            for (int rr = 0; rr < 4; ++rr)
                C[(size_t)(m + rr) * OUT_F + n] = acc[i][j][rr] + bf;
        }
    }
}

extern "C" void kernel_launch(void* const* d_in, const int* in_sizes, int n_in,
                              void* d_out, int out_size, void* d_ws, size_t ws_size,
                              hipStream_t stream) {
    (void)in_sizes; (void)n_in; (void)out_size; (void)ws_size;
    const float* x    = (const float*)d_in[0];
    const int*   wq   = (const int*)d_in[1];     // [524288][12] bytes, widened to int32
    const float* wnrm = (const float*)d_in[2];   // [524288]
    const float* bias = (const float*)d_in[3];   // [4096]
    float* out = (float*)d_out;

    _Float16* w16 = (_Float16*)d_ws;                                     // 32 MB
    _Float16* x16 = (_Float16*)((char*)d_ws + (size_t)OUT_F * IN_F * 2); // 64 MB

    const int NUM_GROUPS = OUT_F * IN_F / 32;  // 524288
    dequant_kernel<<<NUM_GROUPS / 256, 256, 0, stream>>>(wq, wnrm, w16);
    castx_kernel<<<(size_t)M_ROWS * IN_F / 8 / 256, 256, 0, stream>>>(x, x16);

    int grid = (M_ROWS / 256) * (OUT_F / 256);   // 512
    gemm_kernel<<<grid, 512, 0, stream>>>(x16, w16, bias, out);
}